// Round 15
// baseline (102.358 us; speedup 1.0000x reference)
//
#include <hip/hip_runtime.h>
#include <math.h>

// LinearAttention: L=4096, B=4, H=8, D=Dv=64, fp32.
// out[l,b,h,e] = (phiQ[l,bh,:] . kv[bh,:,e]) / (phiQ[l,bh,:] . ksum[bh,:] + eps)
// kv[bh,d,e] = sum_l phiK[l,bh,d] * V[l,bh,e]   (GLOBAL sum)
// phi(x) = elu(x)+1
//
// R15: reduce stage DELETED. P1 (bf16 MFMA, R13-validated math) atomicAdd's
// its partial tile directly into fin in kvT layout (fp32 global atomics,
// device scope); fin is zeroed by hipMemsetAsync first. nchunk 16->32 for
// 4 blocks/CU in P1. P2 = R14 verbatim (R11-validated math).

#define L_TOT 4096
#define NBH   32
#define ROWSTRIDE 2048
#define KVSZ  4160
#define NCHUNK 32
#define EPS_  1e-6f

typedef short s16x8 __attribute__((ext_vector_type(8)));
typedef float f32x4 __attribute__((ext_vector_type(4)));

union FragU { unsigned int u[4]; s16x8 s; };

__device__ __forceinline__ float phi_(float x) {
    return x > 0.0f ? x + 1.0f : __expf(x);
}

__device__ __forceinline__ unsigned int bf16rn_(float x) {
    unsigned int u = __float_as_uint(x);
    return (u + 0x7FFFu + ((u >> 16) & 1u)) >> 16;    // bf16 bits in low16
}

// 8 consecutive u16 (16B, 8B-aligned) -> s16x8, element j = short j
__device__ __forceinline__ s16x8 frag_from_(const unsigned short* p) {
    uint2 a = *(const uint2*)p;
    uint2 b = *(const uint2*)(p + 4);
    FragU f;
    f.u[0] = a.x; f.u[1] = a.y; f.u[2] = b.x; f.u[3] = b.y;
    return f.s;
}

// ---------------- Pass 1: MFMA partial kv + atomic accumulate ----------------
// grid = (NCHUNK=32, 32bh), block 256 (4 waves). Staging/MFMA = R13-verbatim.
// Epilogue: atomicAdd acc into fin[bh] in kvT layout (e*64+d), ksum at 4096+d.
__global__ __launch_bounds__(256) void kv_partial_kernel(
    const float* __restrict__ K, const float* __restrict__ V,
    float* __restrict__ fin, int Lc)
{
    __shared__ __align__(16) unsigned short kphi[64][36];  // 4.5 KB phiK^T
    __shared__ __align__(16) unsigned short vtr [64][36];  // 4.5 KB V^T

    const int tid  = threadIdx.x;
    const int w    = tid >> 6;
    const int lane = tid & 63;
    const int c    = blockIdx.x;
    const int bh   = blockIdx.y;
    const int l0c  = c * Lc;
    const int ntiles = Lc >> 5;            // Lc is a multiple of 32

    const int sr = tid >> 4;               // staging l 0..15 (and +16)
    const int sc = (tid & 15) * 4;         // staging d/e base (float4)
    const size_t bh_off = (size_t)bh * 64;

    const int ar = lane & 15;              // frag row/col within tile
    const int ag = lane >> 4;              // frag k-group (8 l each)

    f32x4 acc[4];                          // d-stripe w x e-tiles 0..3
    f32x4 aks = {0.f, 0.f, 0.f, 0.f};      // ksum stripe w
    #pragma unroll
    for (int n = 0; n < 4; ++n) { f32x4 z = {0.f,0.f,0.f,0.f}; acc[n] = z; }

    FragU onesU;
    #pragma unroll
    for (int p = 0; p < 4; ++p) onesU.u[p] = 0x3F803F80u;  // bf16 1.0 pairs
    const s16x8 ones = onesU.s;

    // prologue loads (tile 0)
    size_t gb = (size_t)(l0c + sr) * ROWSTRIDE + bh_off + sc;
    float4 ka = *(const float4*)(K + gb);
    float4 va = *(const float4*)(V + gb);
    float4 kb = *(const float4*)(K + gb + 16 * ROWSTRIDE);
    float4 vb = *(const float4*)(V + gb + 16 * ROWSTRIDE);

    for (int t = 0; t < ntiles; ++t) {
        {   // transposed staging writes (u16 subword, byte-enable)
            float kx[4] = {ka.x, ka.y, ka.z, ka.w};
            float vx[4] = {va.x, va.y, va.z, va.w};
            float ky[4] = {kb.x, kb.y, kb.z, kb.w};
            float vy[4] = {vb.x, vb.y, vb.z, vb.w};
            #pragma unroll
            for (int i = 0; i < 4; ++i) {
                kphi[sc + i][sr]      = (unsigned short)bf16rn_(phi_(kx[i]));
                kphi[sc + i][sr + 16] = (unsigned short)bf16rn_(phi_(ky[i]));
                vtr [sc + i][sr]      = (unsigned short)bf16rn_(vx[i]);
                vtr [sc + i][sr + 16] = (unsigned short)bf16rn_(vy[i]);
            }
        }
        __syncthreads();

        // prefetch next tile (consumed next iteration)
        if (t + 1 < ntiles) {
            gb = (size_t)(l0c + (t + 1) * 32 + sr) * ROWSTRIDE + bh_off + sc;
            ka = *(const float4*)(K + gb);
            va = *(const float4*)(V + gb);
            kb = *(const float4*)(K + gb + 16 * ROWSTRIDE);
            vb = *(const float4*)(V + gb + 16 * ROWSTRIDE);
        }

        // A-frag: phiK^T, d = w*16+ar, l = ag*8..+7
        const s16x8 afrag = frag_from_(&kphi[w * 16 + ar][ag * 8]);

        #pragma unroll
        for (int nt = 0; nt < 4; ++nt) {
            const s16x8 bfrag = frag_from_(&vtr[nt * 16 + ar][ag * 8]);
            acc[nt] = __builtin_amdgcn_mfma_f32_16x16x32_bf16(afrag, bfrag, acc[nt], 0, 0, 0);
        }
        aks = __builtin_amdgcn_mfma_f32_16x16x32_bf16(afrag, ones, aks, 0, 0, 0);

        __syncthreads();
    }

    // epilogue: atomic accumulate into fin, TRANSPOSED (kvT[e][d])
    float* fb = fin + (size_t)bh * KVSZ;
    #pragma unroll
    for (int nt = 0; nt < 4; ++nt) {
        #pragma unroll
        for (int r = 0; r < 4; ++r) {
            const int d_row = w * 16 + (lane >> 4) * 4 + r;
            const int e_col = nt * 16 + (lane & 15);
            atomicAdd(&fb[e_col * 64 + d_row], acc[nt][r]);
        }
    }
    if ((lane & 15) == 0) {
        #pragma unroll
        for (int r = 0; r < 4; ++r)
            atomicAdd(&fb[4096 + w * 16 + (lane >> 4) * 4 + r], aks[r]);
    }
}

// ---------------- Pass 2: bf16-split MFMA (R14-verbatim) ----------------
__global__ __launch_bounds__(256) void attn_out_kernel(
    const float* __restrict__ Q, const float* __restrict__ fin,
    float* __restrict__ out)
{
    __shared__ __align__(16) unsigned short khi[80 * 72];
    __shared__ __align__(16) unsigned short klo[80 * 72];

    const int tid  = threadIdx.x;
    const int lane = tid & 63;
    const int w    = tid >> 6;
    const int bh   = blockIdx.x & 31;
    const int tg   = blockIdx.x >> 5;
    const int wt0  = tg * 128 + w * 32;

    const float* __restrict__ fb = fin + (size_t)bh * KVSZ;

    // ---- cooperative coalesced staging: 65 rows x 32 float2 units ----
    for (int idx = tid; idx < 2080; idx += 256) {
        const int e = idx >> 5;            // 0..64
        const int p = idx & 31;
        const float2 x2 = *(const float2*)(fb + e * 64 + 2 * p);
        unsigned int u0 = __float_as_uint(x2.x), u1 = __float_as_uint(x2.y);
        unsigned int hi = (u1 & 0xFFFF0000u) | (u0 >> 16);
        float r0 = x2.x - __uint_as_float(u0 & 0xFFFF0000u);
        float r1 = x2.y - __uint_as_float(u1 & 0xFFFF0000u);
        unsigned int lo = (bf16rn_(r1) << 16) | bf16rn_(r0);
        ((unsigned int*)(khi + e * 72))[p] = hi;
        ((unsigned int*)(klo + e * 72))[p] = lo;
    }
    for (int idx = tid; idx < 480; idx += 256) {   // zero rows 65..79
        const int e = 65 + (idx >> 5);
        const int p = idx & 31;
        ((unsigned int*)(khi + e * 72))[p] = 0u;
        ((unsigned int*)(klo + e * 72))[p] = 0u;
    }

    // ---- A-frags from global Q (phi + bf16 split), registers ----
    const int arow = lane & 15;
    const int agrp = lane >> 4;
    s16x8 ahi[2][2], alo[2][2];
    #pragma unroll
    for (int m = 0; m < 2; ++m) {
        #pragma unroll
        for (int kc = 0; kc < 2; ++kc) {
            const float* qp = Q + (size_t)(wt0 + m*16 + arow) * ROWSTRIDE
                                + (size_t)bh * 64 + kc*32 + agrp*8;
            float4 qa = *(const float4*)qp;
            float4 qb = *(const float4*)(qp + 4);
            float x[8] = {qa.x,qa.y,qa.z,qa.w,qb.x,qb.y,qb.z,qb.w};
            FragU fh, fl;
            #pragma unroll
            for (int p = 0; p < 4; ++p) {
                float p0 = phi_(x[2*p]), p1 = phi_(x[2*p+1]);
                unsigned int u0 = __float_as_uint(p0), u1 = __float_as_uint(p1);
                fh.u[p] = (u1 & 0xFFFF0000u) | (u0 >> 16);
                float r0 = p0 - __uint_as_float(u0 & 0xFFFF0000u);
                float r1 = p1 - __uint_as_float(u1 & 0xFFFF0000u);
                fl.u[p] = (bf16rn_(r1) << 16) | bf16rn_(r0);
            }
            ahi[m][kc] = fh.s;
            alo[m][kc] = fl.s;
        }
    }
    __syncthreads();

    f32x4 acc[2][5];
    #pragma unroll
    for (int m = 0; m < 2; ++m) {
        #pragma unroll
        for (int n = 0; n < 5; ++n) { f32x4 z = {0.f,0.f,0.f,0.f}; acc[m][n] = z; }
    }

    #pragma unroll
    for (int nt = 0; nt < 5; ++nt) {
        #pragma unroll
        for (int kc = 0; kc < 2; ++kc) {
            const int off = (nt*16 + arow) * 72 + kc*32 + agrp*8;
            s16x8 bh_ = *(const s16x8*)(khi + off);
            s16x8 bl_ = *(const s16x8*)(klo + off);
            #pragma unroll
            for (int m = 0; m < 2; ++m) {
                acc[m][nt] = __builtin_amdgcn_mfma_f32_16x16x32_bf16(ahi[m][kc], bh_, acc[m][nt], 0, 0, 0);
                acc[m][nt] = __builtin_amdgcn_mfma_f32_16x16x32_bf16(ahi[m][kc], bl_, acc[m][nt], 0, 0, 0);
                acc[m][nt] = __builtin_amdgcn_mfma_f32_16x16x32_bf16(alo[m][kc], bh_, acc[m][nt], 0, 0, 0);
            }
        }
    }

    const int baddr = (lane & 48) << 2;
    float inv[2][4];
    #pragma unroll
    for (int m = 0; m < 2; ++m) {
        #pragma unroll
        for (int r = 0; r < 4; ++r) {
            float dv = __int_as_float(
                __builtin_amdgcn_ds_bpermute(baddr, __float_as_int(acc[m][4][r])));
            inv[m][r] = 1.0f / (dv + EPS_);
        }
    }

    #pragma unroll
    for (int m = 0; m < 2; ++m) {
        #pragma unroll
        for (int r = 0; r < 4; ++r) {
            const int t = wt0 + m*16 + (lane >> 4) * 4 + r;
            float* op = out + (size_t)t * ROWSTRIDE + (size_t)bh * 64 + (lane & 15);
            #pragma unroll
            for (int nt = 0; nt < 4; ++nt)
                op[nt * 16] = acc[m][nt][r] * inv[m][r];
        }
    }
}

extern "C" void kernel_launch(void* const* d_in, const int* in_sizes, int n_in,
                              void* d_out, int out_size, void* d_ws, size_t ws_size,
                              hipStream_t stream) {
    const float* Q = (const float*)d_in[0];
    const float* K = (const float*)d_in[1];
    const float* V = (const float*)d_in[2];
    float* outp = (float*)d_out;
    float* fin  = (float*)d_ws;

    const size_t slab_bytes = (size_t)NBH * KVSZ * sizeof(float);  // 532 KB

    // zero the accumulator (graph-capturable async memset)
    hipMemsetAsync(fin, 0, slab_bytes, stream);

    const int Lc = L_TOT / NCHUNK;       // 128
    hipLaunchKernelGGL(kv_partial_kernel, dim3(NCHUNK, NBH), dim3(256), 0, stream,
                       K, V, fin, Lc);
    hipLaunchKernelGGL(attn_out_kernel, dim3(1024), dim3(256), 0, stream,
                       Q, fin, outp);
}

// Round 16
// 38.435 us; speedup vs baseline: 2.6631x; 2.6631x over previous
//
#include <hip/hip_runtime.h>
#include <math.h>

// LinearAttention: L=4096, B=4, H=8, D=Dv=64, fp32.
// out[l,b,h,e] = (phiQ[l,bh,:] . kv[bh,:,e]) / (phiQ[l,bh,:] . ksum[bh,:] + eps)
// kv[bh,d,e] = sum_l phiK[l,bh,d] * V[l,bh,e]   (GLOBAL sum)
// phi(x) = elu(x)+1
//
// R16 = R13 with a slimmer P2 (R15's atomics reverted — they cost 5x):
//  - P2: 1-term bf16 A (phiQ rounded; drops A-lo conversion + 1/3 of MFMAs)
//  - P2: 512-thr blocks, grid 512 -> staging amortized over 2x tokens
//  - P1 + reduce: R13-verbatim (P1 measured ~90% of its HBM floor)

#define L_TOT 4096
#define NBH   32
#define ROWSTRIDE 2048
#define KVSZ  4160
#define EPS_  1e-6f

typedef short s16x8 __attribute__((ext_vector_type(8)));
typedef float f32x4 __attribute__((ext_vector_type(4)));

union FragU { unsigned int u[4]; s16x8 s; };

__device__ __forceinline__ float phi_(float x) {
    return x > 0.0f ? x + 1.0f : __expf(x);
}

__device__ __forceinline__ unsigned int bf16rn_(float x) {
    unsigned int u = __float_as_uint(x);
    return (u + 0x7FFFu + ((u >> 16) & 1u)) >> 16;    // bf16 bits in low16
}

// 8 consecutive u16 (16B, 8B-aligned) -> s16x8
__device__ __forceinline__ s16x8 frag_from_(const unsigned short* p) {
    uint2 a = *(const uint2*)p;
    uint2 b = *(const uint2*)(p + 4);
    FragU f;
    f.u[0] = a.x; f.u[1] = a.y; f.u[2] = b.x; f.u[3] = b.y;
    return f.s;
}

// ---------------- Pass 1: MFMA partial kv[d][e] + ksum (R13-verbatim) ------
__global__ __launch_bounds__(256) void kv_partial_kernel(
    const float* __restrict__ K, const float* __restrict__ V,
    float* __restrict__ part, int Lc)
{
    __shared__ __align__(16) unsigned short kphi[64][36];  // 4.5 KB phiK^T
    __shared__ __align__(16) unsigned short vtr [64][36];  // 4.5 KB V^T

    const int tid  = threadIdx.x;
    const int w    = tid >> 6;
    const int lane = tid & 63;
    const int c    = blockIdx.x;
    const int bh   = blockIdx.y;
    const int l0c  = c * Lc;
    const int ntiles = Lc >> 5;            // Lc is a multiple of 32

    const int sr = tid >> 4;               // staging l 0..15 (and +16)
    const int sc = (tid & 15) * 4;         // staging d/e base (float4)
    const size_t bh_off = (size_t)bh * 64;

    const int ar = lane & 15;              // frag row/col within tile
    const int ag = lane >> 4;              // frag k-group (8 l each)

    f32x4 acc[4];                          // d-stripe w x e-tiles 0..3
    f32x4 aks = {0.f, 0.f, 0.f, 0.f};      // ksum stripe w
    #pragma unroll
    for (int n = 0; n < 4; ++n) { f32x4 z = {0.f,0.f,0.f,0.f}; acc[n] = z; }

    FragU onesU;
    #pragma unroll
    for (int p = 0; p < 4; ++p) onesU.u[p] = 0x3F803F80u;  // bf16 1.0 pairs
    const s16x8 ones = onesU.s;

    // prologue loads (tile 0)
    size_t gb = (size_t)(l0c + sr) * ROWSTRIDE + bh_off + sc;
    float4 ka = *(const float4*)(K + gb);
    float4 va = *(const float4*)(V + gb);
    float4 kb = *(const float4*)(K + gb + 16 * ROWSTRIDE);
    float4 vb = *(const float4*)(V + gb + 16 * ROWSTRIDE);

    for (int t = 0; t < ntiles; ++t) {
        {   // transposed staging writes (u16 subword, byte-enable)
            float kx[4] = {ka.x, ka.y, ka.z, ka.w};
            float vx[4] = {va.x, va.y, va.z, va.w};
            float ky[4] = {kb.x, kb.y, kb.z, kb.w};
            float vy[4] = {vb.x, vb.y, vb.z, vb.w};
            #pragma unroll
            for (int i = 0; i < 4; ++i) {
                kphi[sc + i][sr]      = (unsigned short)bf16rn_(phi_(kx[i]));
                kphi[sc + i][sr + 16] = (unsigned short)bf16rn_(phi_(ky[i]));
                vtr [sc + i][sr]      = (unsigned short)bf16rn_(vx[i]);
                vtr [sc + i][sr + 16] = (unsigned short)bf16rn_(vy[i]);
            }
        }
        __syncthreads();

        // prefetch next tile (consumed next iteration)
        if (t + 1 < ntiles) {
            gb = (size_t)(l0c + (t + 1) * 32 + sr) * ROWSTRIDE + bh_off + sc;
            ka = *(const float4*)(K + gb);
            va = *(const float4*)(V + gb);
            kb = *(const float4*)(K + gb + 16 * ROWSTRIDE);
            vb = *(const float4*)(V + gb + 16 * ROWSTRIDE);
        }

        // A-frag: phiK^T, d = w*16+ar, l = ag*8..+7
        const s16x8 afrag = frag_from_(&kphi[w * 16 + ar][ag * 8]);

        #pragma unroll
        for (int nt = 0; nt < 4; ++nt) {
            const s16x8 bfrag = frag_from_(&vtr[nt * 16 + ar][ag * 8]);
            acc[nt] = __builtin_amdgcn_mfma_f32_16x16x32_bf16(afrag, bfrag, acc[nt], 0, 0, 0);
        }
        aks = __builtin_amdgcn_mfma_f32_16x16x32_bf16(afrag, ones, aks, 0, 0, 0);

        __syncthreads();
    }

    // epilogue: wave-disjoint stores, kv[d][e] layout
    float* pb = part + ((size_t)c * NBH + bh) * KVSZ;
    #pragma unroll
    for (int nt = 0; nt < 4; ++nt) {
        #pragma unroll
        for (int r = 0; r < 4; ++r) {
            const int d_row = w * 16 + (lane >> 4) * 4 + r;
            const int e_col = nt * 16 + (lane & 15);
            pb[d_row * 64 + e_col] = acc[nt][r];
        }
    }
    if ((lane & 15) == 0) {
        #pragma unroll
        for (int r = 0; r < 4; ++r)
            pb[4096 + w * 16 + (lane >> 4) * 4 + r] = aks[r];
    }
}

// ------- Pass 1b (R13-verbatim): reduce + transpose into fin -------
__global__ __launch_bounds__(256) void kv_reduce_kernel(
    const float* __restrict__ part, float* __restrict__ fin, int nchunk)
{
    const int i4 = blockIdx.x * 256 + threadIdx.x;
    if (i4 >= (NBH * KVSZ) / 4) return;
    const int slab4 = KVSZ / 4;              // 1040
    const int bh = i4 / slab4;
    const int r  = (i4 - bh * slab4) * 4;    // 0..4156, 4-aligned

    float4 s = make_float4(0.f, 0.f, 0.f, 0.f);
    for (int cc = 0; cc < nchunk; ++cc) {
        const float4 v = *(const float4*)(part + ((size_t)cc * NBH + bh) * KVSZ + r);
        s.x += v.x; s.y += v.y; s.z += v.z; s.w += v.w;
    }
    float* fb = fin + (size_t)bh * KVSZ;
    if (r < 4096) {
        const int d = r >> 6;
        const int e = r & 63;                 // e..e+3
        fb[(e + 0) * 64 + d] = s.x;
        fb[(e + 1) * 64 + d] = s.y;
        fb[(e + 2) * 64 + d] = s.z;
        fb[(e + 3) * 64 + d] = s.w;
    } else {
        fb[r + 0] = s.x; fb[r + 1] = s.y; fb[r + 2] = s.z; fb[r + 3] = s.w;
    }
}

// ---------------- Pass 2: bf16 MFMA, 1-term A x 2-term B ----------------
// grid = 512 (16 tg x 32 bh), block = 512 (8 waves x 32 tokens).
// Staging (khi/klo, 2-term kv + ksum row 64 + zero pad) amortized over 256
// tokens/block. A = rounded-bf16 phiQ (1 term). 40 MFMA/wave (was 60).
__global__ __launch_bounds__(512) void attn_out_kernel(
    const float* __restrict__ Q, const float* __restrict__ fin,
    float* __restrict__ out)
{
    __shared__ __align__(16) unsigned short khi[80 * 72];
    __shared__ __align__(16) unsigned short klo[80 * 72];

    const int tid  = threadIdx.x;
    const int lane = tid & 63;
    const int w    = tid >> 6;                 // 0..7
    const int bh   = blockIdx.x & 31;
    const int tg   = blockIdx.x >> 5;          // 0..15
    const int wt0  = tg * 256 + w * 32;        // wave's 32 tokens

    const float* __restrict__ fb = fin + (size_t)bh * KVSZ;

    // ---- cooperative coalesced staging: 65 rows x 32 float2 units ----
    for (int idx = tid; idx < 2080; idx += 512) {
        const int e = idx >> 5;            // 0..64
        const int p = idx & 31;
        const float2 x2 = *(const float2*)(fb + e * 64 + 2 * p);
        unsigned int u0 = __float_as_uint(x2.x), u1 = __float_as_uint(x2.y);
        unsigned int hi = (u1 & 0xFFFF0000u) | (u0 >> 16);
        float r0 = x2.x - __uint_as_float(u0 & 0xFFFF0000u);
        float r1 = x2.y - __uint_as_float(u1 & 0xFFFF0000u);
        unsigned int lo = (bf16rn_(r1) << 16) | bf16rn_(r0);
        ((unsigned int*)(khi + e * 72))[p] = hi;
        ((unsigned int*)(klo + e * 72))[p] = lo;
    }
    for (int idx = tid; idx < 480; idx += 512) {   // zero rows 65..79
        const int e = 65 + (idx >> 5);
        const int p = idx & 31;
        ((unsigned int*)(khi + e * 72))[p] = 0u;
        ((unsigned int*)(klo + e * 72))[p] = 0u;
    }

    // ---- A-frags from global Q: phi -> rounded bf16 (1 term) ----
    const int arow = lane & 15;
    const int agrp = lane >> 4;
    s16x8 ahi[2][2];
    #pragma unroll
    for (int m = 0; m < 2; ++m) {
        #pragma unroll
        for (int kc = 0; kc < 2; ++kc) {
            const float* qp = Q + (size_t)(wt0 + m*16 + arow) * ROWSTRIDE
                                + (size_t)bh * 64 + kc*32 + agrp*8;
            float4 qa = *(const float4*)qp;
            float4 qb = *(const float4*)(qp + 4);
            float x[8] = {qa.x,qa.y,qa.z,qa.w,qb.x,qb.y,qb.z,qb.w};
            FragU fh;
            #pragma unroll
            for (int p = 0; p < 4; ++p) {
                float p0 = phi_(x[2*p]), p1 = phi_(x[2*p+1]);
                fh.u[p] = (bf16rn_(p1) << 16) | bf16rn_(p0);
            }
            ahi[m][kc] = fh.s;
        }
    }
    __syncthreads();

    f32x4 acc[2][5];
    #pragma unroll
    for (int m = 0; m < 2; ++m) {
        #pragma unroll
        for (int n = 0; n < 5; ++n) { f32x4 z = {0.f,0.f,0.f,0.f}; acc[m][n] = z; }
    }

    #pragma unroll
    for (int nt = 0; nt < 5; ++nt) {
        #pragma unroll
        for (int kc = 0; kc < 2; ++kc) {
            const int off = (nt*16 + arow) * 72 + kc*32 + agrp*8;
            s16x8 bh_ = *(const s16x8*)(khi + off);
            s16x8 bl_ = *(const s16x8*)(klo + off);
            #pragma unroll
            for (int m = 0; m < 2; ++m) {
                acc[m][nt] = __builtin_amdgcn_mfma_f32_16x16x32_bf16(ahi[m][kc], bh_, acc[m][nt], 0, 0, 0);
                acc[m][nt] = __builtin_amdgcn_mfma_f32_16x16x32_bf16(ahi[m][kc], bl_, acc[m][nt], 0, 0, 0);
            }
        }
    }

    // den broadcast: den[r'] lives in lane (r'>>2)*16, reg r'&3 (per-wave)
    const int baddr = (lane & 48) << 2;
    float inv[2][4];
    #pragma unroll
    for (int m = 0; m < 2; ++m) {
        #pragma unroll
        for (int r = 0; r < 4; ++r) {
            float dv = __int_as_float(
                __builtin_amdgcn_ds_bpermute(baddr, __float_as_int(acc[m][4][r])));
            inv[m][r] = 1.0f / (dv + EPS_);
        }
    }

    #pragma unroll
    for (int m = 0; m < 2; ++m) {
        #pragma unroll
        for (int r = 0; r < 4; ++r) {
            const int t = wt0 + m*16 + (lane >> 4) * 4 + r;
            float* op = out + (size_t)t * ROWSTRIDE + (size_t)bh * 64 + (lane & 15);
            #pragma unroll
            for (int nt = 0; nt < 4; ++nt)
                op[nt * 16] = acc[m][nt][r] * inv[m][r];
        }
    }
}

extern "C" void kernel_launch(void* const* d_in, const int* in_sizes, int n_in,
                              void* d_out, int out_size, void* d_ws, size_t ws_size,
                              hipStream_t stream) {
    const float* Q = (const float*)d_in[0];
    const float* K = (const float*)d_in[1];
    const float* V = (const float*)d_in[2];
    float* outp = (float*)d_out;
    float* ws   = (float*)d_ws;

    const size_t slab = (size_t)NBH * KVSZ;          // 133120 floats = 532 KB
    const size_t cap  = ws_size / (slab * sizeof(float));

    int nchunk = 1;
    {
        const int cand[4] = {16, 8, 4, 2};
        for (int i = 0; i < 4; ++i) {
            if (cap >= (size_t)cand[i] + 1) { nchunk = cand[i]; break; }
        }
    }
    const int Lc = L_TOT / nchunk;

    float* fin  = ws;
    float* part = ws + slab;     // reduce ALWAYS runs (it does the transpose)

    hipLaunchKernelGGL(kv_partial_kernel, dim3(nchunk, NBH), dim3(256), 0, stream,
                       K, V, part, Lc);
    {
        const int nb = ((NBH * KVSZ) / 4 + 255) / 256;     // 130 blocks
        hipLaunchKernelGGL(kv_reduce_kernel, dim3(nb), dim3(256), 0, stream,
                           part, fin, nchunk);
    }
    hipLaunchKernelGGL(attn_out_kernel, dim3(512), dim3(512), 0, stream,
                       Q, fin, outp);
}